// Round 14
// baseline (85.463 us; speedup 1.0000x reference)
//
#include <hip/hip_runtime.h>
#include <math.h>

// Problem constants
#define BB 8
#define CC 3
#define DD 24
#define HH 128
#define WW 128
#define HW (HH * WW)
#define OCC 16
#define HOUT 126
#define WOUT 126

typedef float f2 __attribute__((ext_vector_type(2)));

// Kernel 1: transpose weights [oc][tap] -> [tap][oc] into d_ws so each tap's
// 16 oc-weights are contiguous (64 B) -> wave-uniform float4 loads become
// s_load_dwordx4/x16 and weights live in SGPRs.
__global__ void wtrans_kernel(const float* __restrict__ wt,
                              float* __restrict__ wT) {
  const int i = blockIdx.x * 256 + threadIdx.x;
  if (i < 81 * 16) {
    const int tap = i >> 4;
    const int oc = i & 15;
    wT[i] = wt[oc * 81 + tap];
  }
}

// ROUND 14: packed fp32 FMAs. The two output columns (z.x = col w0,
// z.y = col w0+1) share each weight, and their x-operands are adjacent
// floats already resident as f2 pairs for kw=0/2; kw=1 uses a middle pair
// (q.y, next.x) built once per (plane,row) per c-group. One v_pk_fma_f32
// per (oc, d, kw) replaces two v_fma_f32 -> VALU instr count halves.
// r13 analysis: we sit at 95% of the m07-measured scalar v_fma_f32 issue
// ceiling (103 TF = 66% duty = our stuck VALUBusy); packing is the only
// VALU-side lever left short of MFMA.
template <int CN>
__device__ __forceinline__ void conv_chunk(const float* __restrict__ xbase,
                                           const float* __restrict__ wT,
                                           float* __restrict__ mn0,
                                           float* __restrict__ mn1) {
  f2 z[CN][OCC];  // .x = col w0, .y = col w0+1
#pragma unroll
  for (int d = 0; d < CN; ++d)
#pragma unroll
    for (int oc = 0; oc < OCC; ++oc) z[d][oc] = (f2)0.f;

#pragma clang loop unroll(disable)
  for (int c = 0; c < 3; ++c) {  // input channel (runtime loop)
    const float* pc = xbase + (size_t)c * DD * HW;
    // Load CN+2 contiguous planes x 3 rows x {lo pair, hi pair}; build the
    // middle pair (cols 1,2) once per (plane,row).
    f2 q0[CN + 2][3], q1[CN + 2][3], qm[CN + 2][3];
#pragma unroll
    for (int p = 0; p < CN + 2; ++p) {
#pragma unroll
      for (int r = 0; r < 3; ++r) {
        const float* rp = pc + (size_t)p * HW + r * WW;
        q0[p][r] = *reinterpret_cast<const f2*>(rp);
        q1[p][r] = *reinterpret_cast<const f2*>(rp + 2);
      }
    }
#pragma unroll
    for (int p = 0; p < CN + 2; ++p) {
#pragma unroll
      for (int r = 0; r < 3; ++r) {
        f2 m;
        m.x = q0[p][r].y;
        m.y = q1[p][r].x;
        qm[p][r] = m;
      }
    }
#pragma unroll
    for (int kd = 0; kd < 3; ++kd) {  // slice = (c, kd)
      const float* wsl = wT + (c * 3 + kd) * 144;
#pragma unroll
      for (int r = 0; r < 3; ++r) {  // kh row
        const float* wp = wsl + r * 48;  // wave-uniform -> SGPRs
#pragma unroll
        for (int kw = 0; kw < 3; ++kw) {
          const float4 wA = *reinterpret_cast<const float4*>(wp + kw * 16 + 0);
          const float4 wB = *reinterpret_cast<const float4*>(wp + kw * 16 + 4);
          const float4 wC = *reinterpret_cast<const float4*>(wp + kw * 16 + 8);
          const float4 wD = *reinterpret_cast<const float4*>(wp + kw * 16 + 12);
#pragma unroll
          for (int d = 0; d < CN; ++d) {
            // output depth d uses input plane kd+d (compile-time index)
            const f2 xp = (kw == 0) ? q0[kd + d][r]
                        : (kw == 1) ? qm[kd + d][r] : q1[kd + d][r];
            f2 w2;
            w2 = wA.x; z[d][0]  = __builtin_elementwise_fma(xp, w2, z[d][0]);
            w2 = wA.y; z[d][1]  = __builtin_elementwise_fma(xp, w2, z[d][1]);
            w2 = wA.z; z[d][2]  = __builtin_elementwise_fma(xp, w2, z[d][2]);
            w2 = wA.w; z[d][3]  = __builtin_elementwise_fma(xp, w2, z[d][3]);
            w2 = wB.x; z[d][4]  = __builtin_elementwise_fma(xp, w2, z[d][4]);
            w2 = wB.y; z[d][5]  = __builtin_elementwise_fma(xp, w2, z[d][5]);
            w2 = wB.z; z[d][6]  = __builtin_elementwise_fma(xp, w2, z[d][6]);
            w2 = wB.w; z[d][7]  = __builtin_elementwise_fma(xp, w2, z[d][7]);
            w2 = wC.x; z[d][8]  = __builtin_elementwise_fma(xp, w2, z[d][8]);
            w2 = wC.y; z[d][9]  = __builtin_elementwise_fma(xp, w2, z[d][9]);
            w2 = wC.z; z[d][10] = __builtin_elementwise_fma(xp, w2, z[d][10]);
            w2 = wC.w; z[d][11] = __builtin_elementwise_fma(xp, w2, z[d][11]);
            w2 = wD.x; z[d][12] = __builtin_elementwise_fma(xp, w2, z[d][12]);
            w2 = wD.y; z[d][13] = __builtin_elementwise_fma(xp, w2, z[d][13]);
            w2 = wD.z; z[d][14] = __builtin_elementwise_fma(xp, w2, z[d][14]);
            w2 = wD.w; z[d][15] = __builtin_elementwise_fma(xp, w2, z[d][15]);
          }
        }
      }
    }
  }

#pragma unroll
  for (int d = 0; d < CN; ++d)
#pragma unroll
    for (int oc = 0; oc < OCC; ++oc) {
      mn0[oc] = fminf(mn0[oc], z[d][oc].x);
      mn1[oc] = fminf(mn1[oc], z[d][oc].y);
    }
}

// Kernel 2: 256-thread blocks = 4 waves; wave g covers dz {0-5,6-11,12-16,
// 17-21} as chunks 3+3 / 3+2. Each lane: 2 adjacent output columns
// (w0 = 2*lane), all 16 channels. 1-D grid, b = wgid&7 pins each batch to
// one XCD (round 7: FETCH 130->18.5 MB). Waves 1..3 publish partial mins to
// LDS; wave 0 merges + softmax + stores.
__global__ __launch_bounds__(256) void conv_min_softmax_kernel(
    const float* __restrict__ x, const float* __restrict__ wT,
    float* __restrict__ out) {
  __shared__ float sm[3][OCC][WOUT];  // 24.2 KB

  const int tid = threadIdx.x;
  const int lane = tid & 63;
  const int g = tid >> 6;  // wave id 0..3
  const int wg = blockIdx.x;
  const int b = wg & 7;    // XCD selector: all h-blocks of batch b -> XCD b
  const int h = wg >> 3;   // 0..125
  const bool active = (lane < 63);          // 63 lanes cover w0 = 0..124
  const int w0 = 2 * (active ? lane : 62);  // clamp inactive lane's addresses

  // dz ranges per wave: {0-5, 6-11, 12-16, 17-21}
  const int dz0 = (g < 2) ? 6 * g : 12 + 5 * (g - 2);

  const float* xw =
      x + (((size_t)b * CC * DD + dz0) * HH + h) * (size_t)WW + w0;

  float mn0[OCC], mn1[OCC];
#pragma unroll
  for (int oc = 0; oc < OCC; ++oc) { mn0[oc] = INFINITY; mn1[oc] = INFINITY; }

  conv_chunk<3>(xw, wT, mn0, mn1);
  if (g < 2) {
    conv_chunk<3>(xw + 3 * (size_t)HW, wT, mn0, mn1);
  } else {
    conv_chunk<2>(xw + 3 * (size_t)HW, wT, mn0, mn1);
  }

  // Waves 1..3 publish partial mins ([oc][w] layout: lanes at w0=2*lane ->
  // 2-way bank aliasing, free).
  if (g > 0 && active) {
#pragma unroll
    for (int oc = 0; oc < OCC; ++oc) {
      sm[g - 1][oc][w0] = mn0[oc];
      sm[g - 1][oc][w0 + 1] = mn1[oc];
    }
  }
  __syncthreads();

  if (g == 0 && active) {
#pragma unroll
    for (int oc = 0; oc < OCC; ++oc) {
      mn0[oc] = fminf(fminf(mn0[oc], sm[0][oc][w0]),
                      fminf(sm[1][oc][w0], sm[2][oc][w0]));
      mn1[oc] = fminf(fminf(mn1[oc], sm[0][oc][w0 + 1]),
                      fminf(sm[1][oc][w0 + 1], sm[2][oc][w0 + 1]));
    }
    float mx0 = mn0[0], mx1 = mn1[0];
#pragma unroll
    for (int oc = 1; oc < OCC; ++oc) {
      mx0 = fmaxf(mx0, mn0[oc]);
      mx1 = fmaxf(mx1, mn1[oc]);
    }
    float e0[OCC], e1[OCC];
    float s0 = 0.f, s1 = 0.f;
#pragma unroll
    for (int oc = 0; oc < OCC; ++oc) {
      e0[oc] = __expf(mn0[oc] - mx0); s0 += e0[oc];
      e1[oc] = __expf(mn1[oc] - mx1); s1 += e1[oc];
    }
    const float i0 = 1.f / s0;
    const float i1 = 1.f / s1;

    float* ob = out + ((size_t)b * OCC * HOUT + h) * (size_t)WOUT + w0;
    const size_t os = (size_t)HOUT * WOUT;
#pragma unroll
    for (int oc = 0; oc < OCC; ++oc) {
      float2 v;
      v.x = e0[oc] * i0;
      v.y = e1[oc] * i1;
      *reinterpret_cast<float2*>(ob + oc * os) = v;  // w0 even -> 8B aligned
    }
  }
}

extern "C" void kernel_launch(void* const* d_in, const int* in_sizes, int n_in,
                              void* d_out, int out_size, void* d_ws, size_t ws_size,
                              hipStream_t stream) {
  const float* x = (const float*)d_in[0];
  const float* wt = (const float*)d_in[1];
  float* out = (float*)d_out;
  float* wT = (float*)d_ws;  // 81*16 floats = 5184 B scratch

  wtrans_kernel<<<dim3(6), dim3(256), 0, stream>>>(wt, wT);

  dim3 grid(1008);          // 1-D: wgid&7 = batch = XCD, wgid>>3 = h
  dim3 block(256, 1, 1);    // 4 waves, dz chunks 3+3 / 3+2, Wtile=2
  conv_min_softmax_kernel<<<grid, block, 0, stream>>>(x, wT, out);
}

// Round 15
// 56.883 us; speedup vs baseline: 1.5024x; 1.5024x over previous
//
#include <hip/hip_runtime.h>
#include <math.h>

// Problem constants
#define BB 8
#define CC 3
#define DD 24
#define HH 128
#define WW 128
#define HW (HH * WW)
#define OCC 16
#define HOUT 126
#define WOUT 126

typedef short bf16x8 __attribute__((ext_vector_type(8)));   // 4 VGPR
typedef float f32x4 __attribute__((ext_vector_type(4)));
typedef unsigned int u32;
typedef u32 u32x4 __attribute__((ext_vector_type(4)));

#define MFMA(a, b, c) __builtin_amdgcn_mfma_f32_16x16x32_bf16((a), (b), (c), 0, 0, 0)

// Build one im2col fragment pair (hi, lo) for depth-plane base pointer xp.
// Slot (g=lane>>4, j) -> k_local = g*8+j in [0,27): (c,kh,kw); voff/msk
// precomputed per lane. hi = truncate-to-bf16 (top 16 bits), lo = exact
// residual truncated to bf16 (error ~2^-16 relative). Pads masked to 0.
__device__ __forceinline__ void build_x_frag(const float* __restrict__ xp,
                                             const int (&voff)[8],
                                             const u32 (&msk)[8],
                                             bf16x8& fh, bf16x8& fl) {
  u32 u[8];
#pragma unroll
  for (int j = 0; j < 8; ++j) {
    const float v = xp[voff[j]];
    u[j] = __float_as_uint(v) & msk[j];
  }
  u32x4 hd, ld;
#pragma unroll
  for (int p = 0; p < 4; ++p) {
    const u32 a = u[2 * p], c = u[2 * p + 1];
    hd[p] = (a >> 16) | (c & 0xffff0000u);
    const float la = __uint_as_float(a) - __uint_as_float(a & 0xffff0000u);
    const float lc = __uint_as_float(c) - __uint_as_float(c & 0xffff0000u);
    ld[p] = (__float_as_uint(la) >> 16) | (__float_as_uint(lc) & 0xffff0000u);
  }
  fh = __builtin_bit_cast(bf16x8, hd);
  fl = __builtin_bit_cast(bf16x8, ld);
}

// One dz step: build the NEW plane (dz+2) fragment into (ch,cl), then 9
// MFMAs: tiles t=0,1,2 (= planes dz,dz+1,dz+2) x {hi*whi, hi*wlo, lo*whi},
// all accumulating into one f32 acc; then min-reduce into mn.
__device__ __forceinline__ void dz_step(const float* __restrict__ xb, int dz,
                                        const int (&voff)[8], const u32 (&msk)[8],
                                        const bf16x8 (&waH)[3], const bf16x8 (&waL)[3],
                                        bf16x8& ah, bf16x8& al,
                                        bf16x8& bh, bf16x8& bl,
                                        bf16x8& ch, bf16x8& cl, f32x4& mn) {
  build_x_frag(xb + (size_t)(dz + 2) * HW, voff, msk, ch, cl);
  f32x4 acc = {0.f, 0.f, 0.f, 0.f};
  acc = MFMA(waH[0], ah, acc); acc = MFMA(waL[0], ah, acc); acc = MFMA(waH[0], al, acc);
  acc = MFMA(waH[1], bh, acc); acc = MFMA(waL[1], bh, acc); acc = MFMA(waH[1], bl, acc);
  acc = MFMA(waH[2], ch, acc); acc = MFMA(waL[2], ch, acc); acc = MFMA(waH[2], cl, acc);
  mn.x = fminf(mn.x, acc.x);
  mn.y = fminf(mn.y, acc.y);
  mn.z = fminf(mn.z, acc.z);
  mn.w = fminf(mn.w, acc.w);
}

// One wave per (b, h, 16-pixel w-tile). Implicit-GEMM: C[oc=16][px=16],
// A = weights (oc x K), B = im2col (K x px), K-tile t = kd-plane with
// k_local = c*9+kh*3+kw (27 real + 5 zero-pad). Advancing dz reuses 2/3
// x-fragments (plane rotation F0,F1,F2). Split-bf16 (hi+lo) recovers fp32
// accuracy; lo*wlo dropped (~2^-16). C/D: col=lane&15=pixel,
// row=(lane>>4)*4+reg=oc (m89-verified). Softmax over oc via 4 regs +
// shfl_xor(16/32). Grid (8,126,8): blockIdx.x=b pins batch->XCD.
__global__ __launch_bounds__(64) void conv_min_softmax_mfma(
    const float* __restrict__ x, const float* __restrict__ wt,
    float* __restrict__ out) {
  const int lane = threadIdx.x;       // 0..63
  const int q15 = lane & 15;          // pixel (B/C col) and oc (A row)
  const int g = lane >> 4;            // k-slot group
  const int b = blockIdx.x;
  const int h = blockIdx.y;
  const int wti = blockIdx.z;
  const int w0 = (wti == 7) ? 110 : wti * 16;  // overlap last tile (no OOB)

  // Per-lane k-slot decode: k_local = g*8+j; (c,kh,kw); pads masked.
  int voff[8];
  u32 msk[8];
#pragma unroll
  for (int j = 0; j < 8; ++j) {
    const int kl = g * 8 + j;
    if (kl < 27) {
      const int c = kl / 9, kh = (kl % 9) / 3, kw = kl % 3;
      voff[j] = c * DD * HW + kh * WW + (w0 + q15 + kw);
      msk[j] = 0xffffffffu;
    } else {
      voff[j] = 0;
      msk[j] = 0u;
    }
  }

  // Weight fragments (A operand), per tile t (= kd): hi/lo split, pads = 0.
  bf16x8 waH[3], waL[3];
#pragma unroll
  for (int t = 0; t < 3; ++t) {
    u32 u[8];
#pragma unroll
    for (int j = 0; j < 8; ++j) {
      const int kl = g * 8 + j;
      float v = 0.f;
      if (kl < 27) {
        const int c = kl / 9, kh = (kl % 9) / 3, kw = kl % 3;
        v = wt[q15 * 81 + c * 27 + t * 9 + kh * 3 + kw];
      }
      u[j] = __float_as_uint(v);
    }
    u32x4 hd, ld;
#pragma unroll
    for (int p = 0; p < 4; ++p) {
      const u32 a = u[2 * p], c = u[2 * p + 1];
      hd[p] = (a >> 16) | (c & 0xffff0000u);
      const float la = __uint_as_float(a) - __uint_as_float(a & 0xffff0000u);
      const float lc = __uint_as_float(c) - __uint_as_float(c & 0xffff0000u);
      ld[p] = (__float_as_uint(la) >> 16) | (__float_as_uint(lc) & 0xffff0000u);
    }
    waH[t] = __builtin_bit_cast(bf16x8, hd);
    waL[t] = __builtin_bit_cast(bf16x8, ld);
  }

  const float* xb = x + ((size_t)b * CC * DD) * HW + (size_t)h * WW;

  // Prologue: planes 0 and 1 into F0, F1.
  bf16x8 f0h, f0l, f1h, f1l, f2h, f2l;
  build_x_frag(xb + (size_t)0 * HW, voff, msk, f0h, f0l);
  build_x_frag(xb + (size_t)1 * HW, voff, msk, f1h, f1l);

  f32x4 mn = {INFINITY, INFINITY, INFINITY, INFINITY};

  // dz = 0..21; rotation period 3 (each step builds plane dz+2).
#pragma clang loop unroll(disable)
  for (int dzb = 0; dzb < 21; dzb += 3) {
    dz_step(xb, dzb + 0, voff, msk, waH, waL, f0h, f0l, f1h, f1l, f2h, f2l, mn);
    dz_step(xb, dzb + 1, voff, msk, waH, waL, f1h, f1l, f2h, f2l, f0h, f0l, mn);
    dz_step(xb, dzb + 2, voff, msk, waH, waL, f2h, f2l, f0h, f0l, f1h, f1l, mn);
  }
  dz_step(xb, 21, voff, msk, waH, waL, f0h, f0l, f1h, f1l, f2h, f2l, mn);

  // Softmax over oc for this lane's pixel: 4 in-lane regs (oc = g*4+r) +
  // lanes sharing q15 across g (xor 16, 32).
  float mx = fmaxf(fmaxf(mn.x, mn.y), fmaxf(mn.z, mn.w));
  mx = fmaxf(mx, __shfl_xor(mx, 16));
  mx = fmaxf(mx, __shfl_xor(mx, 32));
  const float e0 = __expf(mn.x - mx);
  const float e1 = __expf(mn.y - mx);
  const float e2 = __expf(mn.z - mx);
  const float e3 = __expf(mn.w - mx);
  float s = (e0 + e1) + (e2 + e3);
  s += __shfl_xor(s, 16);
  s += __shfl_xor(s, 32);
  const float inv = 1.f / s;

  // Store: out[b][oc = g*4+r][h][w0+q15]; lanes 0..15 of a (g,r) write 16
  // consecutive pixels -> coalesced 64B lines.
  float* ob = out + (((size_t)(b * OCC + g * 4) * HOUT + h) * WOUT) + w0 + q15;
  const size_t os = (size_t)HOUT * WOUT;
  ob[0 * os] = e0 * inv;
  ob[1 * os] = e1 * inv;
  ob[2 * os] = e2 * inv;
  ob[3 * os] = e3 * inv;
}

extern "C" void kernel_launch(void* const* d_in, const int* in_sizes, int n_in,
                              void* d_out, int out_size, void* d_ws, size_t ws_size,
                              hipStream_t stream) {
  const float* x = (const float*)d_in[0];
  const float* wt = (const float*)d_in[1];
  float* out = (float*)d_out;

  dim3 grid(BB, HOUT, 8);   // b (XCD-pinned), h, w-tile
  dim3 block(64, 1, 1);     // one wave per block
  conv_min_softmax_mfma<<<grid, block, 0, stream>>>(x, wt, out);
}

// Round 16
// 40.376 us; speedup vs baseline: 2.1167x; 1.4088x over previous
//
#include <hip/hip_runtime.h>
#include <math.h>

// Problem constants
#define BB 8
#define CC 3
#define DD 24
#define HH 128
#define WW 128
#define HW (HH * WW)
#define OCC 16
#define HOUT 126
#define WOUT 126

typedef short bf16x8 __attribute__((ext_vector_type(8)));   // 4 VGPR
typedef float f32x4 __attribute__((ext_vector_type(4)));
typedef unsigned int u32;
typedef u32 u32x4 __attribute__((ext_vector_type(4)));

#define MFMA(a, b, c) __builtin_amdgcn_mfma_f32_16x16x32_bf16((a), (b), (c), 0, 0, 0)

// Issue the 8 raw fp32 loads of one depth-plane's im2col slots (no pack).
__device__ __forceinline__ void load_raw(const float* __restrict__ xp,
                                         const int (&voff)[8], u32 (&u)[8]) {
#pragma unroll
  for (int j = 0; j < 8; ++j) u[j] = __float_as_uint(xp[voff[j]]);
}

// Pack 8 raw fp32 into split-bf16 fragments: hi = truncate, lo = residual.
__device__ __forceinline__ void pack_frag(const u32 (&u)[8], bf16x8& fh,
                                          bf16x8& fl) {
  u32x4 hd, ld;
#pragma unroll
  for (int p = 0; p < 4; ++p) {
    const u32 a = u[2 * p], c = u[2 * p + 1];
    hd[p] = (a >> 16) | (c & 0xffff0000u);
    const float la = __uint_as_float(a) - __uint_as_float(a & 0xffff0000u);
    const float lc = __uint_as_float(c) - __uint_as_float(c & 0xffff0000u);
    ld[p] = (__float_as_uint(la) >> 16) | (__float_as_uint(lc) & 0xffff0000u);
  }
  fh = __builtin_bit_cast(bf16x8, hd);
  fl = __builtin_bit_cast(bf16x8, fl = __builtin_bit_cast(bf16x8, ld));
}

// One dz step (software-pipelined): FIRST issue plane-pnext loads into upre
// (consumed next step -> a full step of issue distance), THEN pack plane
// dz+2 (loaded last step) into (ch,cl), then 9 MFMAs (3 planes x 3 split
// terms: hi*whi, hi*wlo, lo*whi) and the running min.
__device__ __forceinline__ void dz_step(const float* __restrict__ xb, int pnext,
                                        const int (&voff)[8],
                                        const bf16x8 (&waH)[3], const bf16x8 (&waL)[3],
                                        u32 (&upack)[8], u32 (&upre)[8],
                                        bf16x8& ah, bf16x8& al,
                                        bf16x8& bh, bf16x8& bl,
                                        bf16x8& ch, bf16x8& cl, f32x4& mn) {
  load_raw(xb + (size_t)pnext * HW, voff, upre);
  pack_frag(upack, ch, cl);
  f32x4 acc = {0.f, 0.f, 0.f, 0.f};
  acc = MFMA(waH[0], ah, acc); acc = MFMA(waL[0], ah, acc); acc = MFMA(waH[0], al, acc);
  acc = MFMA(waH[1], bh, acc); acc = MFMA(waL[1], bh, acc); acc = MFMA(waH[1], bl, acc);
  acc = MFMA(waH[2], ch, acc); acc = MFMA(waL[2], ch, acc); acc = MFMA(waH[2], cl, acc);
  mn.x = fminf(mn.x, acc.x);
  mn.y = fminf(mn.y, acc.y);
  mn.z = fminf(mn.z, acc.z);
  mn.w = fminf(mn.w, acc.w);
}

// 256-thread blocks = 4 independent waves, wave wv handles w-tile
// wti = blockIdx.z*4+wv (r15 was 64-thread blocks -> per-CU workgroup cap
// stranded occupancy at ~8.6 waves/CU). Implicit-GEMM per wave:
// C[oc=16][px=16] via mfma_f32_16x16x32_bf16, A = weights (oc x K),
// B = im2col (K x px), K-tile t = kd-plane, k_local = c*9+kh*3+kw (27 real
// + 5 pad slots; pads zeroed on the A side only — x is finite). Split-bf16
// recovers fp32 accuracy (lo*wlo dropped, ~2^-16). Plane rotation F0..F2
// reuses 2/3 fragments per dz; raw double-buffer U0/U1 gives loads a full
// step of latency cover. C/D: col=lane&15=pixel, row=(lane>>4)*4+reg=oc.
__global__ __launch_bounds__(256) void conv_min_softmax_mfma(
    const float* __restrict__ x, const float* __restrict__ wt,
    float* __restrict__ out) {
  const int tid = threadIdx.x;
  const int lane = tid & 63;
  const int wv = tid >> 6;            // wave id 0..3
  const int q15 = lane & 15;          // pixel (B col) and oc (A row)
  const int g = lane >> 4;            // k-slot group
  const int b = blockIdx.x;
  const int h = blockIdx.y;
  const int wti = blockIdx.z * 4 + wv;
  const int w0 = (wti == 7) ? 110 : wti * 16;  // overlap last tile (no OOB)

  // Per-lane k-slot decode: k_local = g*8+j -> (c,kh,kw); pads -> offset 0.
  int voff[8];
#pragma unroll
  for (int j = 0; j < 8; ++j) {
    const int kl = g * 8 + j;
    if (kl < 27) {
      const int c = kl / 9, kh = (kl % 9) / 3, kw = kl % 3;
      voff[j] = c * DD * HW + kh * WW + (w0 + q15 + kw);
    } else {
      voff[j] = 0;  // finite dummy; A-side weight is 0 for pad slots
    }
  }

  // Weight fragments (A), per kd-tile t: hi/lo split, pad slots = 0.
  bf16x8 waH[3], waL[3];
#pragma unroll
  for (int t = 0; t < 3; ++t) {
    u32 u[8];
#pragma unroll
    for (int j = 0; j < 8; ++j) {
      const int kl = g * 8 + j;
      float v = 0.f;
      if (kl < 27) {
        const int c = kl / 9, kh = (kl % 9) / 3, kw = kl % 3;
        v = wt[q15 * 81 + c * 27 + t * 9 + kh * 3 + kw];
      }
      u[j] = __float_as_uint(v);
    }
    u32x4 hd, ld;
#pragma unroll
    for (int p = 0; p < 4; ++p) {
      const u32 a = u[2 * p], c = u[2 * p + 1];
      hd[p] = (a >> 16) | (c & 0xffff0000u);
      const float la = __uint_as_float(a) - __uint_as_float(a & 0xffff0000u);
      const float lc = __uint_as_float(c) - __uint_as_float(c & 0xffff0000u);
      ld[p] = (__float_as_uint(la) >> 16) | (__float_as_uint(lc) & 0xffff0000u);
    }
    waH[t] = __builtin_bit_cast(bf16x8, hd);
    waL[t] = __builtin_bit_cast(bf16x8, ld);
  }

  const float* xb = x + ((size_t)b * CC * DD) * HW + (size_t)h * WW;

  // Prologue: planes 0,1 packed immediately; plane 2 raw in U0.
  u32 u0[8], u1[8];
  bf16x8 f0h, f0l, f1h, f1l, f2h, f2l;
  load_raw(xb + (size_t)0 * HW, voff, u0);
  load_raw(xb + (size_t)1 * HW, voff, u1);
  pack_frag(u0, f0h, f0l);
  pack_frag(u1, f1h, f1l);
  load_raw(xb + (size_t)2 * HW, voff, u0);

  f32x4 mn = {INFINITY, INFINITY, INFINITY, INFINITY};

  // dz = 0..17: period-6 rotation (U parity x F rotation), runtime loop.
#pragma clang loop unroll(disable)
  for (int dzb = 0; dzb < 18; dzb += 6) {
    dz_step(xb, dzb + 3, voff, waH, waL, u0, u1, f0h, f0l, f1h, f1l, f2h, f2l, mn);
    dz_step(xb, dzb + 4, voff, waH, waL, u1, u0, f1h, f1l, f2h, f2l, f0h, f0l, mn);
    dz_step(xb, dzb + 5, voff, waH, waL, u0, u1, f2h, f2l, f0h, f0l, f1h, f1l, mn);
    dz_step(xb, dzb + 6, voff, waH, waL, u1, u0, f0h, f0l, f1h, f1l, f2h, f2l, mn);
    dz_step(xb, dzb + 7, voff, waH, waL, u0, u1, f1h, f1l, f2h, f2l, f0h, f0l, mn);
    dz_step(xb, dzb + 8, voff, waH, waL, u1, u0, f2h, f2l, f0h, f0l, f1h, f1l, mn);
  }
  // Tail dz = 18..21 (prefetch clamped to plane 23).
  dz_step(xb, 21, voff, waH, waL, u0, u1, f0h, f0l, f1h, f1l, f2h, f2l, mn);
  dz_step(xb, 22, voff, waH, waL, u1, u0, f1h, f1l, f2h, f2l, f0h, f0l, mn);
  dz_step(xb, 23, voff, waH, waL, u0, u1, f2h, f2l, f0h, f0l, f1h, f1l, mn);
  dz_step(xb, 23, voff, waH, waL, u1, u0, f0h, f0l, f1h, f1l, f2h, f2l, mn);

  // Softmax over oc for this lane's pixel: 4 in-lane regs (oc = g*4+r) +
  // lanes sharing q15 across g (xor 16, 32).
  float mx = fmaxf(fmaxf(mn.x, mn.y), fmaxf(mn.z, mn.w));
  mx = fmaxf(mx, __shfl_xor(mx, 16));
  mx = fmaxf(mx, __shfl_xor(mx, 32));
  const float e0 = __expf(mn.x - mx);
  const float e1 = __expf(mn.y - mx);
  const float e2 = __expf(mn.z - mx);
  const float e3 = __expf(mn.w - mx);
  float s = (e0 + e1) + (e2 + e3);
  s += __shfl_xor(s, 16);
  s += __shfl_xor(s, 32);
  const float inv = 1.f / s;

  // Store: out[b][oc = g*4+r][h][w0+q15]; 16 consecutive pixels per (g,r).
  float* ob = out + (((size_t)(b * OCC + g * 4) * HOUT + h) * WOUT) + w0 + q15;
  const size_t os = (size_t)HOUT * WOUT;
  ob[0 * os] = e0 * inv;
  ob[1 * os] = e1 * inv;
  ob[2 * os] = e2 * inv;
  ob[3 * os] = e3 * inv;
}

extern "C" void kernel_launch(void* const* d_in, const int* in_sizes, int n_in,
                              void* d_out, int out_size, void* d_ws, size_t ws_size,
                              hipStream_t stream) {
  const float* x = (const float*)d_in[0];
  const float* wt = (const float*)d_in[1];
  float* out = (float*)d_out;

  dim3 grid(BB, HOUT, 2);   // b (XCD-pinned), h, w-tile-pair
  dim3 block(256, 1, 1);    // 4 waves = 4 w-tiles
  conv_min_softmax_mfma<<<grid, block, 0, stream>>>(x, wt, out);
}

// Round 17
// 36.151 us; speedup vs baseline: 2.3641x; 1.1169x over previous
//
#include <hip/hip_runtime.h>
#include <math.h>

// Problem constants
#define BB 8
#define CC 3
#define DD 24
#define HH 128
#define WW 128
#define HW (HH * WW)
#define OCC 16
#define HOUT 126
#define WOUT 126

typedef short bf16x8 __attribute__((ext_vector_type(8)));   // 4 VGPR
typedef float f32x4 __attribute__((ext_vector_type(4)));
typedef unsigned int u32;
typedef u32 u32x4 __attribute__((ext_vector_type(4)));

#define MFMA(a, b, c) __builtin_amdgcn_mfma_f32_16x16x32_bf16((a), (b), (c), 0, 0, 0)
// Pack the top halves of two f32 (a=even slot, c=odd slot) into one dword:
// result = (a>>16) | (c & 0xffff0000)  ==  v_perm_b32(hi=c, lo=a, 0x07060302)
#define PKHI(a, c) __builtin_amdgcn_perm((c), (a), 0x07060302u)

// Issue the 8 raw fp32 loads of one depth-plane's im2col slots (no pack).
__device__ __forceinline__ void load_raw(const float* __restrict__ xp,
                                         const int (&voff)[8], u32 (&u)[8]) {
#pragma unroll
  for (int j = 0; j < 8; ++j) u[j] = __float_as_uint(xp[voff[j]]);
}

// Pack 8 raw fp32 into split-bf16 fragments: hi = truncate (1 perm/pair),
// lo = residual x - trunc(x) truncated to bf16 (and+sub per value + perm).
__device__ __forceinline__ void pack_frag(const u32 (&u)[8], bf16x8& fh,
                                          bf16x8& fl) {
  u32x4 hd, ld;
#pragma unroll
  for (int p = 0; p < 4; ++p) {
    const u32 a = u[2 * p], c = u[2 * p + 1];
    hd[p] = PKHI(a, c);
    const float la = __uint_as_float(a) - __uint_as_float(a & 0xffff0000u);
    const float lc = __uint_as_float(c) - __uint_as_float(c & 0xffff0000u);
    ld[p] = PKHI(__float_as_uint(la), __float_as_uint(lc));
  }
  fh = __builtin_bit_cast(bf16x8, hd);
  fl = __builtin_bit_cast(bf16x8, ld);
}

// One dz step (software-pipelined): FIRST issue plane-pnext loads into upre
// (consumed next step -> a full step of issue distance), THEN pack plane
// dz+2 (loaded last step) into (ch,cl), then 6 MFMAs (3 planes x
// {x_hi*w, x_lo*w}; w is single-term RTN-bf16) and the running min.
__device__ __forceinline__ void dz_step(const float* __restrict__ xb, int pnext,
                                        const int (&voff)[8],
                                        const bf16x8 (&wa)[3],
                                        u32 (&upack)[8], u32 (&upre)[8],
                                        bf16x8& ah, bf16x8& al,
                                        bf16x8& bh, bf16x8& bl,
                                        bf16x8& ch, bf16x8& cl, f32x4& mn) {
  load_raw(xb + (size_t)pnext * HW, voff, upre);
  pack_frag(upack, ch, cl);
  f32x4 acc = {0.f, 0.f, 0.f, 0.f};
  acc = MFMA(wa[0], ah, acc); acc = MFMA(wa[0], al, acc);
  acc = MFMA(wa[1], bh, acc); acc = MFMA(wa[1], bl, acc);
  acc = MFMA(wa[2], ch, acc); acc = MFMA(wa[2], cl, acc);
  mn.x = fminf(mn.x, acc.x);
  mn.y = fminf(mn.y, acc.y);
  mn.z = fminf(mn.z, acc.z);
  mn.w = fminf(mn.w, acc.w);
}

// 256-thread blocks = 4 independent waves, wave wv handles w-tile
// wti = blockIdx.z*4+wv. Implicit-GEMM per wave: C[oc=16][px=16] via
// mfma_f32_16x16x32_bf16, A = weights (oc x K, RTN-bf16 single term),
// B = im2col (K x px, split-bf16 hi+lo), K-tile t = kd-plane,
// k_local = c*9+kh*3+kw (27 real + 5 pad; pads zeroed on A side).
// y = (x_hi+x_lo)*w_rtn: error ~ x*(w-w_rtn) ~ 2^-10 rel (r17: dropped
// x_hi*w_lo term; was 9 MFMA). Plane rotation F0..F2 reuses 2/3 fragments
// per dz; raw double-buffer U0/U1 covers load latency. C/D layout:
// col=lane&15=pixel, row=(lane>>4)*4+reg=oc (m89-verified, r15-validated).
__global__ __launch_bounds__(256) void conv_min_softmax_mfma(
    const float* __restrict__ x, const float* __restrict__ wt,
    float* __restrict__ out) {
  const int tid = threadIdx.x;
  const int lane = tid & 63;
  const int wv = tid >> 6;            // wave id 0..3
  const int q15 = lane & 15;          // pixel (B col) and oc (A row)
  const int g = lane >> 4;            // k-slot group
  const int b = blockIdx.x;
  const int h = blockIdx.y;
  const int wti = blockIdx.z * 4 + wv;
  const int w0 = (wti == 7) ? 110 : wti * 16;  // overlap last tile (no OOB)

  // Per-lane k-slot decode: k_local = g*8+j -> (c,kh,kw); pads -> offset 0.
  int voff[8];
#pragma unroll
  for (int j = 0; j < 8; ++j) {
    const int kl = g * 8 + j;
    if (kl < 27) {
      const int c = kl / 9, kh = (kl % 9) / 3, kw = kl % 3;
      voff[j] = c * DD * HW + kh * WW + (w0 + q15 + kw);
    } else {
      voff[j] = 0;  // finite dummy; A-side weight is 0 for pad slots
    }
  }

  // Weight fragments (A), per kd-tile t: single-term RTN bf16, pads = 0.
  bf16x8 wa[3];
#pragma unroll
  for (int t = 0; t < 3; ++t) {
    u32 u[8];
#pragma unroll
    for (int j = 0; j < 8; ++j) {
      const int kl = g * 8 + j;
      float v = 0.f;
      if (kl < 27) {
        const int c = kl / 9, kh = (kl % 9) / 3, kw = kl % 3;
        v = wt[q15 * 81 + c * 27 + t * 9 + kh * 3 + kw];
      }
      const u32 ub = __float_as_uint(v);
      u[j] = ub + 0x7fffu + ((ub >> 16) & 1u);  // round-to-nearest-even bf16
    }
    u32x4 hd;
#pragma unroll
    for (int p = 0; p < 4; ++p) hd[p] = PKHI(u[2 * p], u[2 * p + 1]);
    wa[t] = __builtin_bit_cast(bf16x8, hd);
  }

  const float* xb = x + ((size_t)b * CC * DD) * HW + (size_t)h * WW;

  // Prologue: planes 0,1 packed immediately; plane 2 raw in U0.
  u32 u0[8], u1[8];
  bf16x8 f0h, f0l, f1h, f1l, f2h, f2l;
  load_raw(xb + (size_t)0 * HW, voff, u0);
  load_raw(xb + (size_t)1 * HW, voff, u1);
  pack_frag(u0, f0h, f0l);
  pack_frag(u1, f1h, f1l);
  load_raw(xb + (size_t)2 * HW, voff, u0);

  f32x4 mn = {INFINITY, INFINITY, INFINITY, INFINITY};

  // dz = 0..17: period-6 rotation (U parity x F rotation), runtime loop.
#pragma clang loop unroll(disable)
  for (int dzb = 0; dzb < 18; dzb += 6) {
    dz_step(xb, dzb + 3, voff, wa, u0, u1, f0h, f0l, f1h, f1l, f2h, f2l, mn);
    dz_step(xb, dzb + 4, voff, wa, u1, u0, f1h, f1l, f2h, f2l, f0h, f0l, mn);
    dz_step(xb, dzb + 5, voff, wa, u0, u1, f2h, f2l, f0h, f0l, f1h, f1l, mn);
    dz_step(xb, dzb + 6, voff, wa, u1, u0, f0h, f0l, f1h, f1l, f2h, f2l, mn);
    dz_step(xb, dzb + 7, voff, wa, u0, u1, f1h, f1l, f2h, f2l, f0h, f0l, mn);
    dz_step(xb, dzb + 8, voff, wa, u1, u0, f2h, f2l, f0h, f0l, f1h, f1l, mn);
  }
  // Tail dz = 18..21 (prefetch clamped to plane 23).
  dz_step(xb, 21, voff, wa, u0, u1, f0h, f0l, f1h, f1l, f2h, f2l, mn);
  dz_step(xb, 22, voff, wa, u1, u0, f1h, f1l, f2h, f2l, f0h, f0l, mn);
  dz_step(xb, 23, voff, wa, u0, u1, f2h, f2l, f0h, f0l, f1h, f1l, mn);
  dz_step(xb, 23, voff, wa, u1, u0, f0h, f0l, f1h, f1l, f2h, f2l, mn);

  // Softmax over oc for this lane's pixel: 4 in-lane regs (oc = g*4+r) +
  // lanes sharing q15 across g (xor 16, 32).
  float mx = fmaxf(fmaxf(mn.x, mn.y), fmaxf(mn.z, mn.w));
  mx = fmaxf(mx, __shfl_xor(mx, 16));
  mx = fmaxf(mx, __shfl_xor(mx, 32));
  const float e0 = __expf(mn.x - mx);
  const float e1 = __expf(mn.y - mx);
  const float e2 = __expf(mn.z - mx);
  const float e3 = __expf(mn.w - mx);
  float s = (e0 + e1) + (e2 + e3);
  s += __shfl_xor(s, 16);
  s += __shfl_xor(s, 32);
  const float inv = 1.f / s;

  // Store: out[b][oc = g*4+r][h][w0+q15]; 16 consecutive pixels per (g,r).
  float* ob = out + (((size_t)(b * OCC + g * 4) * HOUT + h) * WOUT) + w0 + q15;
  const size_t os = (size_t)HOUT * WOUT;
  ob[0 * os] = e0 * inv;
  ob[1 * os] = e1 * inv;
  ob[2 * os] = e2 * inv;
  ob[3 * os] = e3 * inv;
}

extern "C" void kernel_launch(void* const* d_in, const int* in_sizes, int n_in,
                              void* d_out, int out_size, void* d_ws, size_t ws_size,
                              hipStream_t stream) {
  const float* x = (const float*)d_in[0];
  const float* wt = (const float*)d_in[1];
  float* out = (float*)d_out;

  dim3 grid(BB, HOUT, 2);   // b (XCD-pinned), h, w-tile-pair
  dim3 block(256, 1, 1);    // 4 waves = 4 w-tiles
  conv_min_softmax_mfma<<<grid, block, 0, stream>>>(x, wt, out);
}